// Round 7
// baseline (103.955 us; speedup 1.0000x reference)
//
#include <hip/hip_runtime.h>

#define P 256     // H*W
#define CDIM 256
#define SDIM 32

typedef __attribute__((ext_vector_type(8))) short short8;   // 8 bf16 = 4 VGPR
typedef __attribute__((ext_vector_type(4))) float f32x4;
typedef __attribute__((ext_vector_type(4))) unsigned int uint4v;

__device__ inline unsigned int pack2bf(float lo, float hi) {
    unsigned int ul = __builtin_bit_cast(unsigned int, lo);
    unsigned int uh = __builtin_bit_cast(unsigned int, hi);
    ul += 0x7fffu + ((ul >> 16) & 1u);   // RNE
    uh += 0x7fffu + ((uh >> 16) & 1u);
    return (ul >> 16) | (uh & 0xffff0000u);
}

// Fused prep. Blocks [0,512): eh (8 a-rows x 256 p each, plenty of parallelism —
// round-5's fusion failure was 64-block starvation, geometry kept at 512 here).
// Blocks [512,544): pack W1e -> bf16 MFMA-A-fragment-linear
// ([m'=a>>4][kc=k>>3][i16=a&15][8 bf16] -> af load = lane-linear 16B).
__global__ __launch_bounds__(256) void prep_kernel(const float* __restrict__ hid,
                                                   const float* __restrict__ W1,
                                                   const float* __restrict__ b1,
                                                   float* __restrict__ ehb1,
                                                   uint4v* __restrict__ packA) {
    const int blk = blockIdx.x;
    const int tid = threadIdx.x;
    if (blk >= 512) {
        // ---- pack W1e ----
        const int t  = (blk - 512) * 256 + tid;   // [0, 8192)
        const int a  = ((t >> 9) << 4) | (t & 15);
        const int kc = (t >> 4) & 31;
        const float* src = W1 + (size_t)a * 512 + 256 + kc * 8;
        const float4 f0 = *(const float4*)src;
        const float4 f1 = *(const float4*)(src + 4);
        uint4v u;
        u.x = pack2bf(f0.x, f0.y);
        u.y = pack2bf(f0.z, f0.w);
        u.z = pack2bf(f1.x, f1.y);
        u.w = pack2bf(f1.z, f1.w);
        packA[t] = u;
        return;
    }
    // ---- eh: ehb1[b,a,p] = sum_c W1h[a,c]*hid[b,c,p] + b1[a]  (fp32, exact) ----
    const int b  = blk >> 5;
    const int a0 = (blk & 31) << 3;    // 8 a-rows per block (uniform -> s_load W1)
    const int p  = tid;
    float acc[8];
#pragma unroll
    for (int i = 0; i < 8; ++i) acc[i] = 0.f;
    const float* hb = hid + (size_t)b * CDIM * P;
    for (int c = 0; c < CDIM; c += 8) {
        float hv[8];
#pragma unroll
        for (int j = 0; j < 8; ++j) hv[j] = hb[(c + j) * P + p];
#pragma unroll
        for (int i = 0; i < 8; ++i) {
            const float* wr = W1 + (size_t)(a0 + i) * 512 + c;
#pragma unroll
            for (int j = 0; j < 8; ++j) acc[i] = fmaf(wr[j], hv[j], acc[i]);
        }
    }
#pragma unroll
    for (int i = 0; i < 8; ++i)
        ehb1[((size_t)b * CDIM + a0 + i) * P + p] = acc[i] + b1[a0 + i];
}

// Kernel B: bf16-MFMA energy. Block = 256 thr / 4 waves, tile 256a x 64p.
// grid = (bs, p-quarter) -> enc fetched exactly once, FULLY COALESCED:
//   G: float4 stream in native [c][p] order -> regs
//   W1: regs -> fp32 LDS tile [64c][64p], XOR-swizzled, b128 conflict-free
//   R/W2: LDS transpose: 16 b32 reads (XOR-spread, <=2-way = free), pack bf16,
//         b128 write into the proven [64p][64c] fragment tile (double-buffered).
// A fragments: direct global_load_dwordx4 from packA (L2-resident).
__global__ __launch_bounds__(256, 3) void energy_mfma(const float* __restrict__ enc,
                                                      const unsigned char* __restrict__ packA,
                                                      const float* __restrict__ W2,
                                                      const float* __restrict__ ehb1,
                                                      float* __restrict__ partial) {
    __shared__ __align__(16) unsigned char ldsF[64 * 256];     // fp32 [64c][64p] swz (16KB)
    __shared__ __align__(16) unsigned char ldsB[2][64 * 128];  // bf16 [64p][64c] swz (2x8KB)
    __shared__ float red[4];
    const int bid = blockIdx.x;          // 2048
    const int bs  = bid >> 2;            // b*32+s
    const int pq  = bid & 3;             // p-quarter (64p)
    const int b   = bs >> 5;
    const int tid = threadIdx.x;
    const int l   = tid & 63;
    const int w   = tid >> 6;            // wave 0..3 -> a-slice
    const int g   = l >> 4;
    const int i16 = l & 15;
    const int a_base = w * 64;
    const int cg4 = tid >> 4;            // G: c-row (within 16-row round)
    const int p4  = tid & 15;            // G: float4 column
    const int p_r = tid & 63;            // R: pixel
    const int ch  = tid >> 6;            // R: 16-c group (== wave)
    const float* eb = enc + (size_t)bs * (CDIM * P) + pq * 64;

    f32x4 acc[4][4];
#pragma unroll
    for (int m = 0; m < 4; ++m)
#pragma unroll
        for (int n = 0; n < 4; ++n) acc[m][n] = (f32x4){0.f, 0.f, 0.f, 0.f};

    // ---- prologue: stage tile 0 ----
    {
        float4 gv[4];
#pragma unroll
        for (int r = 0; r < 4; ++r)
            gv[r] = *(const float4*)(eb + (size_t)(r * 16 + cg4) * P + p4 * 4);
#pragma unroll
        for (int r = 0; r < 4; ++r) {
            const int c = r * 16 + cg4;
            *(float4*)(ldsF + c * 256 + ((p4 * 16) ^ ((c & 7) << 4))) = gv[r];
        }
    }
    __syncthreads();
    {
        float cv[16];
#pragma unroll
        for (int j = 0; j < 16; ++j) {
            const int c = ch * 16 + j;
            cv[j] = *(const float*)(ldsF + c * 256 +
                     ((((p_r >> 2) * 16) ^ ((c & 7) << 4)) | ((p_r & 3) * 4)));
        }
        unsigned char* dst = ldsB[0] + p_r * 128;
#pragma unroll
        for (int h = 0; h < 2; ++h) {
            uint4v u;
            u.x = pack2bf(cv[h*8+0], cv[h*8+1]);
            u.y = pack2bf(cv[h*8+2], cv[h*8+3]);
            u.z = pack2bf(cv[h*8+4], cv[h*8+5]);
            u.w = pack2bf(cv[h*8+6], cv[h*8+7]);
            *(uint4v*)(dst + ((ch * 32 + h * 16) ^ ((p_r & 7) << 4))) = u;
        }
    }
    __syncthreads();

#pragma unroll
    for (int kt = 0; kt < 4; ++kt) {
        // issue next-kt coalesced enc loads (hide HBM under MFMA)
        float4 gv[4];
        if (kt < 3) {
#pragma unroll
            for (int r = 0; r < 4; ++r)
                gv[r] = *(const float4*)(eb + (size_t)((kt + 1) * 64 + r * 16 + cg4) * P + p4 * 4);
        }
        // A fragments for this kt (L2 hits)
        short8 af[2][4];
#pragma unroll
        for (int kh = 0; kh < 2; ++kh)
#pragma unroll
            for (int m = 0; m < 4; ++m) {
                const int chunk = ((a_base >> 4) + m) * 32 + kt * 8 + kh * 4;
                af[kh][m] = __builtin_bit_cast(short8,
                    *(const uint4v*)(packA + (size_t)chunk * 256 + l * 16));
            }
        // MFMA on current buffer
#pragma unroll
        for (int kh = 0; kh < 2; ++kh) {
            short8 bf[4];
#pragma unroll
            for (int n = 0; n < 4; ++n) {
                const int row = n * 16 + i16;
                bf[n] = __builtin_bit_cast(short8,
                    *(const uint4v*)(ldsB[kt & 1] + row * 128 +
                                     (((kh * 4 + g) * 16) ^ ((row & 7) << 4))));
            }
#pragma unroll
            for (int m = 0; m < 4; ++m)
#pragma unroll
                for (int n = 0; n < 4; ++n)
                    acc[m][n] = __builtin_amdgcn_mfma_f32_16x16x32_bf16(af[kh][m], bf[n], acc[m][n], 0, 0, 0);
        }
        // transpose-stage next tile: fp32 tile write, barrier, LDS transpose+pack
        if (kt < 3) {
#pragma unroll
            for (int r = 0; r < 4; ++r) {
                const int c = r * 16 + cg4;
                *(float4*)(ldsF + c * 256 + ((p4 * 16) ^ ((c & 7) << 4))) = gv[r];
            }
            __syncthreads();
            float cv[16];
#pragma unroll
            for (int j = 0; j < 16; ++j) {
                const int c = ch * 16 + j;
                cv[j] = *(const float*)(ldsF + c * 256 +
                         ((((p_r >> 2) * 16) ^ ((c & 7) << 4)) | ((p_r & 3) * 4)));
            }
            unsigned char* dst = ldsB[(kt + 1) & 1] + p_r * 128;
#pragma unroll
            for (int h = 0; h < 2; ++h) {
                uint4v u;
                u.x = pack2bf(cv[h*8+0], cv[h*8+1]);
                u.y = pack2bf(cv[h*8+2], cv[h*8+3]);
                u.z = pack2bf(cv[h*8+4], cv[h*8+5]);
                u.w = pack2bf(cv[h*8+6], cv[h*8+7]);
                *(uint4v*)(dst + ((ch * 32 + h * 16) ^ ((p_r & 7) << 4))) = u;
            }
            __syncthreads();
        }
    }

    // epilogue: x = acc + ehb1; tanh; dot W2; block-reduce
    float ep = 0.f;
    const float* ehbB = ehb1 + (size_t)b * (CDIM * P);
#pragma unroll
    for (int m = 0; m < 4; ++m) {
#pragma unroll
        for (int r = 0; r < 4; ++r) {
            const int a = a_base + m * 16 + g * 4 + r;   // C/D: row=(lane>>4)*4+reg
            const float w2v = W2[a];
            const float* ehr = ehbB + (size_t)a * P + pq * 64 + i16;
#pragma unroll
            for (int n = 0; n < 4; ++n) {
                const float x  = acc[m][n][r] + ehr[n * 16];
                const float ex = __expf(2.f * x);
                const float t  = 1.f - 2.f / (ex + 1.f);
                ep = fmaf(w2v, t, ep);
            }
        }
    }
#pragma unroll
    for (int off = 32; off > 0; off >>= 1) ep += __shfl_down(ep, off, 64);
    if (l == 0) red[w] = ep;
    __syncthreads();
    if (tid == 0)
        partial[(size_t)bs * 4 + pq] = red[0] + red[1] + red[2] + red[3];
}

// Kernel D: fused softmax + context. Each block computes its batch's 32-wide
// softmax from the 128 block-uniform partials (s_loads), then the weighted sum.
__global__ __launch_bounds__(256) void context_kernel(const float4* __restrict__ enc4,
                                                      const float* __restrict__ partial,
                                                      const float* __restrict__ b2,
                                                      float4* __restrict__ out4) {
    const int bi = blockIdx.x;                       // 1024
    const int b  = bi >> 6;
    const int i4 = ((bi & 63) << 8) + threadIdx.x;   // [0,16384) float4s over C*P

    float e[SDIM];
    const float* pb = partial + (size_t)b * SDIM * 4;
    const float bias = b2[0];
#pragma unroll
    for (int s = 0; s < SDIM; ++s)
        e[s] = (pb[s*4] + pb[s*4+1] + pb[s*4+2] + pb[s*4+3]) * (1.f / 256.f) + bias;
    float m = e[0];
#pragma unroll
    for (int s = 1; s < SDIM; ++s) m = fmaxf(m, e[s]);
    float sum = 0.f;
#pragma unroll
    for (int s = 0; s < SDIM; ++s) { e[s] = __expf(e[s] - m); sum += e[s]; }
    const float inv = 1.f / sum;

    float4 acc = {0.f, 0.f, 0.f, 0.f};
    const float4* eb = enc4 + (size_t)b * SDIM * 16384 + i4;
#pragma unroll 4
    for (int s = 0; s < SDIM; ++s) {
        const float wv = e[s] * inv;
        const float4 v = eb[(size_t)s * 16384];
        acc.x = fmaf(wv, v.x, acc.x);
        acc.y = fmaf(wv, v.y, acc.y);
        acc.z = fmaf(wv, v.z, acc.z);
        acc.w = fmaf(wv, v.w, acc.w);
    }
    out4[(size_t)b * 16384 + i4] = acc;
}

extern "C" void kernel_launch(void* const* d_in, const int* in_sizes, int n_in,
                              void* d_out, int out_size, void* d_ws, size_t ws_size,
                              hipStream_t stream) {
    const float* hid = (const float*)d_in[0];
    const float* enc = (const float*)d_in[1];
    const float* W1  = (const float*)d_in[2];
    const float* b1  = (const float*)d_in[3];
    const float* W2  = (const float*)d_in[4];
    const float* b2  = (const float*)d_in[5];
    float* out = (float*)d_out;

    float* ehb1    = out;                       // d_out reused as 4MB scratch
    float* partial = (float*)d_ws;              // 2048 floats
    unsigned char* packA = (unsigned char*)(partial + 2048);  // 128KB bf16 W1e

    prep_kernel<<<544, 256, 0, stream>>>(hid, W1, b1, ehb1, (uint4v*)packA);
    energy_mfma<<<2048, 256, 0, stream>>>(enc, packA, W2, ehb1, partial);
    context_kernel<<<1024, 256, 0, stream>>>((const float4*)enc, partial, b2, (float4*)out);
}

// Round 8
// 90.944 us; speedup vs baseline: 1.1431x; 1.1431x over previous
//
#include <hip/hip_runtime.h>

#define P 256     // H*W
#define CDIM 256
#define SDIM 32

typedef __attribute__((ext_vector_type(8))) short short8;   // 8 bf16 = 4 VGPR
typedef __attribute__((ext_vector_type(4))) float f32x4;
typedef __attribute__((ext_vector_type(4))) unsigned int uint4v;

__device__ inline unsigned int pack2bf(float lo, float hi) {
    unsigned int ul = __builtin_bit_cast(unsigned int, lo);
    unsigned int uh = __builtin_bit_cast(unsigned int, hi);
    ul += 0x7fffu + ((ul >> 16) & 1u);   // RNE
    uh += 0x7fffu + ((uh >> 16) & 1u);
    return (ul >> 16) | (uh & 0xffff0000u);
}

// Fused prep. Blocks [0,512): eh. Blocks [512,544): pack W1e -> bf16
// MFMA-A-fragment-linear ([m'=a>>4][kc=k>>3][i16=a&15][8 bf16]).
__global__ __launch_bounds__(256) void prep_kernel(const float* __restrict__ hid,
                                                   const float* __restrict__ W1,
                                                   const float* __restrict__ b1,
                                                   float* __restrict__ ehb1,
                                                   uint4v* __restrict__ packA) {
    const int blk = blockIdx.x;
    const int tid = threadIdx.x;
    if (blk >= 512) {
        const int t  = (blk - 512) * 256 + tid;   // [0, 8192)
        const int a  = ((t >> 9) << 4) | (t & 15);
        const int kc = (t >> 4) & 31;
        const float* src = W1 + (size_t)a * 512 + 256 + kc * 8;
        const float4 f0 = *(const float4*)src;
        const float4 f1 = *(const float4*)(src + 4);
        uint4v u;
        u.x = pack2bf(f0.x, f0.y);
        u.y = pack2bf(f0.z, f0.w);
        u.z = pack2bf(f1.x, f1.y);
        u.w = pack2bf(f1.z, f1.w);
        packA[t] = u;
        return;
    }
    // eh: ehb1[b,a,p] = sum_c W1h[a,c]*hid[b,c,p] + b1[a]  (fp32, exact)
    const int b  = blk >> 5;
    const int a0 = (blk & 31) << 3;    // 8 a-rows per block (uniform -> s_load W1)
    const int p  = tid;
    float acc[8];
#pragma unroll
    for (int i = 0; i < 8; ++i) acc[i] = 0.f;
    const float* hb = hid + (size_t)b * CDIM * P;
    for (int c = 0; c < CDIM; c += 8) {
        float hv[8];
#pragma unroll
        for (int j = 0; j < 8; ++j) hv[j] = hb[(c + j) * P + p];
#pragma unroll
        for (int i = 0; i < 8; ++i) {
            const float* wr = W1 + (size_t)(a0 + i) * 512 + c;
#pragma unroll
            for (int j = 0; j < 8; ++j) acc[i] = fmaf(wr[j], hv[j], acc[i]);
        }
    }
#pragma unroll
    for (int i = 0; i < 8; ++i)
        ehb1[((size_t)b * CDIM + a0 + i) * P + p] = acc[i] + b1[a0 + i];
}

// Kernel B: bf16-MFMA energy. Block = 256 thr / 4 waves, tile 256a x 64p.
// ISSUE ORDER IS THE POINT: af (L2) loads issue BEFORE gv (HBM) prefetch so the
// MFMA wait is vmcnt(#gv) not vmcnt(0) — prefetch stays in flight (AITER pattern).
__global__ __launch_bounds__(256, 3) void energy_mfma(const float* __restrict__ enc,
                                                      const unsigned char* __restrict__ packA,
                                                      const float* __restrict__ W2,
                                                      const float* __restrict__ ehb1,
                                                      float* __restrict__ partial) {
    __shared__ __align__(16) unsigned char ldsF[64 * 256];     // fp32 [64c][64p] swz (16KB)
    __shared__ __align__(16) unsigned char ldsB[2][64 * 128];  // bf16 [64p][64c] swz (2x8KB)
    __shared__ float red[4];
    const int bid = blockIdx.x;          // 2048
    const int bs  = bid >> 2;            // b*32+s
    const int pq  = bid & 3;             // p-quarter (64p)
    const int b   = bs >> 5;
    const int tid = threadIdx.x;
    const int l   = tid & 63;
    const int w   = tid >> 6;            // wave 0..3 -> a-slice
    const int g   = l >> 4;
    const int i16 = l & 15;
    const int a_base = w * 64;
    const int cg4 = tid >> 4;            // G: c-row (within 16-row round)
    const int p4  = tid & 15;            // G: float4 column
    const int p_r = tid & 63;            // R: pixel
    const int ch  = tid >> 6;            // R: 16-c group (== wave)
    const float* eb = enc + (size_t)bs * (CDIM * P) + pq * 64;

    f32x4 acc[4][4];
#pragma unroll
    for (int m = 0; m < 4; ++m)
#pragma unroll
        for (int n = 0; n < 4; ++n) acc[m][n] = (f32x4){0.f, 0.f, 0.f, 0.f};

    // ---- prologue: stage tile 0 ----
    {
        float4 gv[4];
#pragma unroll
        for (int r = 0; r < 4; ++r)
            gv[r] = *(const float4*)(eb + (size_t)(r * 16 + cg4) * P + p4 * 4);
#pragma unroll
        for (int r = 0; r < 4; ++r) {
            const int c = r * 16 + cg4;
            *(float4*)(ldsF + c * 256 + ((p4 * 16) ^ ((c & 7) << 4))) = gv[r];
        }
    }
    __syncthreads();
    {
        float cv[16];
#pragma unroll
        for (int j = 0; j < 16; ++j) {
            const int c = ch * 16 + j;
            cv[j] = *(const float*)(ldsF + c * 256 +
                     ((((p_r >> 2) * 16) ^ ((c & 7) << 4)) | ((p_r & 3) * 4)));
        }
        unsigned char* dst = ldsB[0] + p_r * 128;
#pragma unroll
        for (int h = 0; h < 2; ++h) {
            uint4v u;
            u.x = pack2bf(cv[h*8+0], cv[h*8+1]);
            u.y = pack2bf(cv[h*8+2], cv[h*8+3]);
            u.z = pack2bf(cv[h*8+4], cv[h*8+5]);
            u.w = pack2bf(cv[h*8+6], cv[h*8+7]);
            *(uint4v*)(dst + ((ch * 32 + h * 16) ^ ((p_r & 7) << 4))) = u;
        }
    }
    __syncthreads();

#pragma unroll
    for (int kt = 0; kt < 4; ++kt) {
        // A fragments FIRST (L2 hits) — MFMA will wait vmcnt(#gv), not 0
        short8 af[2][4];
#pragma unroll
        for (int kh = 0; kh < 2; ++kh)
#pragma unroll
            for (int m = 0; m < 4; ++m) {
                const int chunk = ((a_base >> 4) + m) * 32 + kt * 8 + kh * 4;
                af[kh][m] = __builtin_bit_cast(short8,
                    *(const uint4v*)(packA + (size_t)chunk * 256 + l * 16));
            }
        __builtin_amdgcn_sched_barrier(0);   // pin: af issue before gv issue
        // next-kt coalesced enc prefetch (stays in flight across the MFMAs)
        float4 gv[4];
        if (kt < 3) {
#pragma unroll
            for (int r = 0; r < 4; ++r)
                gv[r] = *(const float4*)(eb + (size_t)((kt + 1) * 64 + r * 16 + cg4) * P + p4 * 4);
        }
        // MFMA on current buffer
#pragma unroll
        for (int kh = 0; kh < 2; ++kh) {
            short8 bf[4];
#pragma unroll
            for (int n = 0; n < 4; ++n) {
                const int row = n * 16 + i16;
                bf[n] = __builtin_bit_cast(short8,
                    *(const uint4v*)(ldsB[kt & 1] + row * 128 +
                                     (((kh * 4 + g) * 16) ^ ((row & 7) << 4))));
            }
#pragma unroll
            for (int m = 0; m < 4; ++m)
#pragma unroll
                for (int n = 0; n < 4; ++n)
                    acc[m][n] = __builtin_amdgcn_mfma_f32_16x16x32_bf16(af[kh][m], bf[n], acc[m][n], 0, 0, 0);
        }
        // transpose-stage next tile: fp32 tile write, barrier, LDS transpose+pack
        if (kt < 3) {
#pragma unroll
            for (int r = 0; r < 4; ++r) {
                const int c = r * 16 + cg4;
                *(float4*)(ldsF + c * 256 + ((p4 * 16) ^ ((c & 7) << 4))) = gv[r];
            }
            __syncthreads();
            float cv[16];
#pragma unroll
            for (int j = 0; j < 16; ++j) {
                const int c = ch * 16 + j;
                cv[j] = *(const float*)(ldsF + c * 256 +
                         ((((p_r >> 2) * 16) ^ ((c & 7) << 4)) | ((p_r & 3) * 4)));
            }
            unsigned char* dst = ldsB[(kt + 1) & 1] + p_r * 128;
#pragma unroll
            for (int h = 0; h < 2; ++h) {
                uint4v u;
                u.x = pack2bf(cv[h*8+0], cv[h*8+1]);
                u.y = pack2bf(cv[h*8+2], cv[h*8+3]);
                u.z = pack2bf(cv[h*8+4], cv[h*8+5]);
                u.w = pack2bf(cv[h*8+6], cv[h*8+7]);
                *(uint4v*)(dst + ((ch * 32 + h * 16) ^ ((p_r & 7) << 4))) = u;
            }
            __syncthreads();
        }
    }

    // epilogue: x = acc + ehb1; tanh; dot W2; block-reduce
    float ep = 0.f;
    const float* ehbB = ehb1 + (size_t)b * (CDIM * P);
#pragma unroll
    for (int m = 0; m < 4; ++m) {
#pragma unroll
        for (int r = 0; r < 4; ++r) {
            const int a = a_base + m * 16 + g * 4 + r;   // C/D: row=(lane>>4)*4+reg
            const float w2v = W2[a];
            const float* ehr = ehbB + (size_t)a * P + pq * 64 + i16;
#pragma unroll
            for (int n = 0; n < 4; ++n) {
                const float x  = acc[m][n][r] + ehr[n * 16];
                const float ex = __expf(2.f * x);
                const float t  = 1.f - 2.f / (ex + 1.f);
                ep = fmaf(w2v, t, ep);
            }
        }
    }
#pragma unroll
    for (int off = 32; off > 0; off >>= 1) ep += __shfl_down(ep, off, 64);
    if (l == 0) red[w] = ep;
    __syncthreads();
    if (tid == 0)
        partial[(size_t)bs * 4 + pq] = red[0] + red[1] + red[2] + red[3];
}

// Kernel D: fused softmax + context. Each block computes its batch's 32-wide
// softmax from the 128 block-uniform partials (s_loads), then the weighted sum.
__global__ __launch_bounds__(256) void context_kernel(const float4* __restrict__ enc4,
                                                      const float* __restrict__ partial,
                                                      const float* __restrict__ b2,
                                                      float4* __restrict__ out4) {
    const int bi = blockIdx.x;                       // 1024
    const int b  = bi >> 6;
    const int i4 = ((bi & 63) << 8) + threadIdx.x;   // [0,16384) float4s over C*P

    float e[SDIM];
    const float* pb = partial + (size_t)b * SDIM * 4;
    const float bias = b2[0];
#pragma unroll
    for (int s = 0; s < SDIM; ++s)
        e[s] = (pb[s*4] + pb[s*4+1] + pb[s*4+2] + pb[s*4+3]) * (1.f / 256.f) + bias;
    float m = e[0];
#pragma unroll
    for (int s = 1; s < SDIM; ++s) m = fmaxf(m, e[s]);
    float sum = 0.f;
#pragma unroll
    for (int s = 0; s < SDIM; ++s) { e[s] = __expf(e[s] - m); sum += e[s]; }
    const float inv = 1.f / sum;

    float4 acc = {0.f, 0.f, 0.f, 0.f};
    const float4* eb = enc4 + (size_t)b * SDIM * 16384 + i4;
#pragma unroll 4
    for (int s = 0; s < SDIM; ++s) {
        const float wv = e[s] * inv;
        const float4 v = eb[(size_t)s * 16384];
        acc.x = fmaf(wv, v.x, acc.x);
        acc.y = fmaf(wv, v.y, acc.y);
        acc.z = fmaf(wv, v.z, acc.z);
        acc.w = fmaf(wv, v.w, acc.w);
    }
    out4[(size_t)b * 16384 + i4] = acc;
}

extern "C" void kernel_launch(void* const* d_in, const int* in_sizes, int n_in,
                              void* d_out, int out_size, void* d_ws, size_t ws_size,
                              hipStream_t stream) {
    const float* hid = (const float*)d_in[0];
    const float* enc = (const float*)d_in[1];
    const float* W1  = (const float*)d_in[2];
    const float* b1  = (const float*)d_in[3];
    const float* W2  = (const float*)d_in[4];
    const float* b2  = (const float*)d_in[5];
    float* out = (float*)d_out;

    float* ehb1    = out;                       // d_out reused as 4MB scratch
    float* partial = (float*)d_ws;              // 2048 floats
    unsigned char* packA = (unsigned char*)(partial + 2048);  // 128KB bf16 W1e

    prep_kernel<<<544, 256, 0, stream>>>(hid, W1, b1, ehb1, (uint4v*)packA);
    energy_mfma<<<2048, 256, 0, stream>>>(enc, packA, W2, ehb1, partial);
    context_kernel<<<1024, 256, 0, stream>>>((const float4*)enc, partial, b2, (float4*)out);
}

// Round 9
// 88.276 us; speedup vs baseline: 1.1776x; 1.0302x over previous
//
#include <hip/hip_runtime.h>

#define P 256     // H*W
#define CDIM 256
#define SDIM 32

typedef __attribute__((ext_vector_type(8))) short short8;   // 8 bf16 = 4 VGPR
typedef __attribute__((ext_vector_type(4))) float f32x4;
typedef __attribute__((ext_vector_type(4))) unsigned int uint4v;

__device__ inline unsigned int pack2bf(float lo, float hi) {
    unsigned int ul = __builtin_bit_cast(unsigned int, lo);
    unsigned int uh = __builtin_bit_cast(unsigned int, hi);
    ul += 0x7fffu + ((ul >> 16) & 1u);   // RNE
    uh += 0x7fffu + ((uh >> 16) & 1u);
    return (ul >> 16) | (uh & 0xffff0000u);
}

// Fused prep. Blocks [0,512): eh. Blocks [512,544): pack W1e -> bf16
// MFMA-A-fragment-linear ([m'=a>>4][kc=k>>3][i16=a&15][8 bf16]).
__global__ __launch_bounds__(256) void prep_kernel(const float* __restrict__ hid,
                                                   const float* __restrict__ W1,
                                                   const float* __restrict__ b1,
                                                   float* __restrict__ ehb1,
                                                   uint4v* __restrict__ packA) {
    const int blk = blockIdx.x;
    const int tid = threadIdx.x;
    if (blk >= 512) {
        const int t  = (blk - 512) * 256 + tid;   // [0, 8192)
        const int a  = ((t >> 9) << 4) | (t & 15);
        const int kc = (t >> 4) & 31;
        const float* src = W1 + (size_t)a * 512 + 256 + kc * 8;
        const float4 f0 = *(const float4*)src;
        const float4 f1 = *(const float4*)(src + 4);
        uint4v u;
        u.x = pack2bf(f0.x, f0.y);
        u.y = pack2bf(f0.z, f0.w);
        u.z = pack2bf(f1.x, f1.y);
        u.w = pack2bf(f1.z, f1.w);
        packA[t] = u;
        return;
    }
    // eh: ehb1[b,a,p] = sum_c W1h[a,c]*hid[b,c,p] + b1[a]  (fp32, exact)
    const int b  = blk >> 5;
    const int a0 = (blk & 31) << 3;    // 8 a-rows per block (uniform -> s_load W1)
    const int p  = tid;
    float acc[8];
#pragma unroll
    for (int i = 0; i < 8; ++i) acc[i] = 0.f;
    const float* hb = hid + (size_t)b * CDIM * P;
    for (int c = 0; c < CDIM; c += 8) {
        float hv[8];
#pragma unroll
        for (int j = 0; j < 8; ++j) hv[j] = hb[(c + j) * P + p];
#pragma unroll
        for (int i = 0; i < 8; ++i) {
            const float* wr = W1 + (size_t)(a0 + i) * 512 + c;
#pragma unroll
            for (int j = 0; j < 8; ++j) acc[i] = fmaf(wr[j], hv[j], acc[i]);
        }
    }
#pragma unroll
    for (int i = 0; i < 8; ++i)
        ehb1[((size_t)b * CDIM + a0 + i) * P + p] = acc[i] + b1[a0 + i];
}

// Kernel B: bf16-MFMA energy. Block = 256 thr / 4 waves, tile 256a x 64p.
// acc is INITIALIZED from ehb1 (C/D-layout fragment loads in the prologue,
// hidden under tile-0 HBM wait) -> epilogue is pure VALU (no load chain).
// af (L2) issue BEFORE gv (HBM) prefetch each kt (vmcnt stays >0, AITER rule).
__global__ __launch_bounds__(256, 3) void energy_mfma(const float* __restrict__ enc,
                                                      const unsigned char* __restrict__ packA,
                                                      const float* __restrict__ W2,
                                                      const float* __restrict__ ehb1,
                                                      float* __restrict__ partial) {
    __shared__ __align__(16) unsigned char ldsF[64 * 256];     // fp32 [64c][64p] swz (16KB)
    __shared__ __align__(16) unsigned char ldsB[2][64 * 128];  // bf16 [64p][64c] swz (2x8KB)
    __shared__ float red[4];
    const int bid = blockIdx.x;          // 2048
    const int bs  = bid >> 2;            // b*32+s
    const int pq  = bid & 3;             // p-quarter (64p)
    const int b   = bs >> 5;
    const int tid = threadIdx.x;
    const int l   = tid & 63;
    const int w   = tid >> 6;            // wave 0..3 -> a-slice
    const int g   = l >> 4;
    const int i16 = l & 15;
    const int a_base = w * 64;
    const int cg4 = tid >> 4;            // G: c-row (within 16-row round)
    const int p4  = tid & 15;            // G: float4 column
    const int p_r = tid & 63;            // R: pixel
    const int ch  = tid >> 6;            // R: 16-c group (== wave)
    const float* eb = enc + (size_t)bs * (CDIM * P) + pq * 64;
    const float* ehbB = ehb1 + (size_t)b * (CDIM * P) + pq * 64;

    // ---- prologue: issue tile-0 HBM loads first ----
    float4 gv0[4];
#pragma unroll
    for (int r = 0; r < 4; ++r)
        gv0[r] = *(const float4*)(eb + (size_t)(r * 16 + cg4) * P + p4 * 4);
    __builtin_amdgcn_sched_barrier(0);

    // acc init from ehb1 fragment (C/D layout: row=(lane>>4)*4+reg, col=lane&15)
    // + W2 preload; all independent loads, hidden under the gv0 HBM wait.
    f32x4 acc[4][4];
    float w2v[4][4];
#pragma unroll
    for (int m = 0; m < 4; ++m) {
#pragma unroll
        for (int r = 0; r < 4; ++r) {
            const int a = a_base + m * 16 + g * 4 + r;
            w2v[m][r] = W2[a];
            const float* ehr = ehbB + (size_t)a * P + i16;
#pragma unroll
            for (int n = 0; n < 4; ++n)
                acc[m][n][r] = ehr[n * 16];
        }
    }
    __builtin_amdgcn_sched_barrier(0);

    // stage tile 0: fp32 swizzled LDS tile
#pragma unroll
    for (int r = 0; r < 4; ++r) {
        const int c = r * 16 + cg4;
        *(float4*)(ldsF + c * 256 + ((p4 * 16) ^ ((c & 7) << 4))) = gv0[r];
    }
    __syncthreads();
    {
        float cv[16];
#pragma unroll
        for (int j = 0; j < 16; ++j) {
            const int c = ch * 16 + j;
            cv[j] = *(const float*)(ldsF + c * 256 +
                     ((((p_r >> 2) * 16) ^ ((c & 7) << 4)) | ((p_r & 3) * 4)));
        }
        unsigned char* dst = ldsB[0] + p_r * 128;
#pragma unroll
        for (int h = 0; h < 2; ++h) {
            uint4v u;
            u.x = pack2bf(cv[h*8+0], cv[h*8+1]);
            u.y = pack2bf(cv[h*8+2], cv[h*8+3]);
            u.z = pack2bf(cv[h*8+4], cv[h*8+5]);
            u.w = pack2bf(cv[h*8+6], cv[h*8+7]);
            *(uint4v*)(dst + ((ch * 32 + h * 16) ^ ((p_r & 7) << 4))) = u;
        }
    }
    __syncthreads();

#pragma unroll
    for (int kt = 0; kt < 4; ++kt) {
        // A fragments FIRST (L2 hits) — MFMA wait is vmcnt(#gv), not 0
        short8 af[2][4];
#pragma unroll
        for (int kh = 0; kh < 2; ++kh)
#pragma unroll
            for (int m = 0; m < 4; ++m) {
                const int chunk = ((a_base >> 4) + m) * 32 + kt * 8 + kh * 4;
                af[kh][m] = __builtin_bit_cast(short8,
                    *(const uint4v*)(packA + (size_t)chunk * 256 + l * 16));
            }
        __builtin_amdgcn_sched_barrier(0);   // pin: af issue before gv issue
        // next-kt coalesced enc prefetch (stays in flight across the MFMAs)
        float4 gv[4];
        if (kt < 3) {
#pragma unroll
            for (int r = 0; r < 4; ++r)
                gv[r] = *(const float4*)(eb + (size_t)((kt + 1) * 64 + r * 16 + cg4) * P + p4 * 4);
        }
        // MFMA on current buffer
#pragma unroll
        for (int kh = 0; kh < 2; ++kh) {
            short8 bf[4];
#pragma unroll
            for (int n = 0; n < 4; ++n) {
                const int row = n * 16 + i16;
                bf[n] = __builtin_bit_cast(short8,
                    *(const uint4v*)(ldsB[kt & 1] + row * 128 +
                                     (((kh * 4 + g) * 16) ^ ((row & 7) << 4))));
            }
#pragma unroll
            for (int m = 0; m < 4; ++m)
#pragma unroll
                for (int n = 0; n < 4; ++n)
                    acc[m][n] = __builtin_amdgcn_mfma_f32_16x16x32_bf16(af[kh][m], bf[n], acc[m][n], 0, 0, 0);
        }
        // transpose-stage next tile: fp32 tile write, barrier, LDS transpose+pack
        if (kt < 3) {
#pragma unroll
            for (int r = 0; r < 4; ++r) {
                const int c = r * 16 + cg4;
                *(float4*)(ldsF + c * 256 + ((p4 * 16) ^ ((c & 7) << 4))) = gv[r];
            }
            __syncthreads();
            float cv[16];
#pragma unroll
            for (int j = 0; j < 16; ++j) {
                const int c = ch * 16 + j;
                cv[j] = *(const float*)(ldsF + c * 256 +
                         ((((p_r >> 2) * 16) ^ ((c & 7) << 4)) | ((p_r & 3) * 4)));
            }
            unsigned char* dst = ldsB[(kt + 1) & 1] + p_r * 128;
#pragma unroll
            for (int h = 0; h < 2; ++h) {
                uint4v u;
                u.x = pack2bf(cv[h*8+0], cv[h*8+1]);
                u.y = pack2bf(cv[h*8+2], cv[h*8+3]);
                u.z = pack2bf(cv[h*8+4], cv[h*8+5]);
                u.w = pack2bf(cv[h*8+6], cv[h*8+7]);
                *(uint4v*)(dst + ((ch * 32 + h * 16) ^ ((p_r & 7) << 4))) = u;
            }
            __syncthreads();
        }
    }

    // epilogue: pure VALU — tanh + W2 dot, 4 independent m-chains
    float epm[4];
#pragma unroll
    for (int m = 0; m < 4; ++m) {
        float e = 0.f;
#pragma unroll
        for (int r = 0; r < 4; ++r) {
            const float wv = w2v[m][r];
#pragma unroll
            for (int n = 0; n < 4; ++n) {
                const float x  = acc[m][n][r];
                const float ex = __expf(2.f * x);
                const float t  = 1.f - 2.f / (ex + 1.f);
                e = fmaf(wv, t, e);
            }
        }
        epm[m] = e;
    }
    float ep = (epm[0] + epm[1]) + (epm[2] + epm[3]);
#pragma unroll
    for (int off = 32; off > 0; off >>= 1) ep += __shfl_down(ep, off, 64);
    if (l == 0) red[w] = ep;
    __syncthreads();
    if (tid == 0)
        partial[(size_t)bs * 4 + pq] = red[0] + red[1] + red[2] + red[3];
}

// Kernel D: fused softmax + context. Each block computes its batch's 32-wide
// softmax from the 128 block-uniform partials (s_loads), then the weighted sum.
__global__ __launch_bounds__(256) void context_kernel(const float4* __restrict__ enc4,
                                                      const float* __restrict__ partial,
                                                      const float* __restrict__ b2,
                                                      float4* __restrict__ out4) {
    const int bi = blockIdx.x;                       // 1024
    const int b  = bi >> 6;
    const int i4 = ((bi & 63) << 8) + threadIdx.x;   // [0,16384) float4s over C*P

    float e[SDIM];
    const float* pb = partial + (size_t)b * SDIM * 4;
    const float bias = b2[0];
#pragma unroll
    for (int s = 0; s < SDIM; ++s)
        e[s] = (pb[s*4] + pb[s*4+1] + pb[s*4+2] + pb[s*4+3]) * (1.f / 256.f) + bias;
    float m = e[0];
#pragma unroll
    for (int s = 1; s < SDIM; ++s) m = fmaxf(m, e[s]);
    float sum = 0.f;
#pragma unroll
    for (int s = 0; s < SDIM; ++s) { e[s] = __expf(e[s] - m); sum += e[s]; }
    const float inv = 1.f / sum;

    float4 acc = {0.f, 0.f, 0.f, 0.f};
    const float4* eb = enc4 + (size_t)b * SDIM * 16384 + i4;
#pragma unroll 4
    for (int s = 0; s < SDIM; ++s) {
        const float wv = e[s] * inv;
        const float4 v = eb[(size_t)s * 16384];
        acc.x = fmaf(wv, v.x, acc.x);
        acc.y = fmaf(wv, v.y, acc.y);
        acc.z = fmaf(wv, v.z, acc.z);
        acc.w = fmaf(wv, v.w, acc.w);
    }
    out4[(size_t)b * 16384 + i4] = acc;
}

extern "C" void kernel_launch(void* const* d_in, const int* in_sizes, int n_in,
                              void* d_out, int out_size, void* d_ws, size_t ws_size,
                              hipStream_t stream) {
    const float* hid = (const float*)d_in[0];
    const float* enc = (const float*)d_in[1];
    const float* W1  = (const float*)d_in[2];
    const float* b1  = (const float*)d_in[3];
    const float* W2  = (const float*)d_in[4];
    const float* b2  = (const float*)d_in[5];
    float* out = (float*)d_out;

    float* ehb1    = out;                       // d_out reused as 4MB scratch
    float* partial = (float*)d_ws;              // 2048 floats
    unsigned char* packA = (unsigned char*)(partial + 2048);  // 128KB bf16 W1e

    prep_kernel<<<544, 256, 0, stream>>>(hid, W1, b1, ehb1, (uint4v*)packA);
    energy_mfma<<<2048, 256, 0, stream>>>(enc, packA, W2, ehb1, partial);
    context_kernel<<<1024, 256, 0, stream>>>((const float4*)enc, partial, b2, (float4*)out);
}